// Round 20
// baseline (207.666 us; speedup 1.0000x reference)
//
#include <hip/hip_runtime.h>
#include <math.h>

typedef _Float16 half8 __attribute__((ext_vector_type(8)));
typedef float floatx4 __attribute__((ext_vector_type(4)));

#define DD 256
#define HH 512
#define OC 92
#define NJ 24
#define BM 64                  // rows per block (4 waves x 16)
#define NCHUNK 16
#define W2_OFF 131072          // halfs: compact W2 frag region (16 chunks x 3072 halfs)
#define FLAG_OFF 180224        // halfs offset of int flag block
#define FCAP 16384
#define BUF_BYTES 16384        // W1 chunk (W2 read global->reg)

__constant__ int c_parent[NJ] = {-1,0,0,0,1,2,3,4,5,6,7,8,9,9,9,12,13,14,16,17,18,19,20,21};

// fragment maps (verified R2-R19):
// A/B-frag: lane l holds (non-K idx)=l&15, k = 4*(l>>4)+(j&3)+16*(j>>2)
// C/D: reg i: M-idx = 4*(l>>4)+i, N-idx = l&15
// Swapped GEMM1: mfma(W1frag, zfrag) -> lane holds batch-row=l&15, h-col=16*cf+4*(l>>4)+i
//   == GEMM2 B-frag with j = i|(cf<<2)  (register handoff, no LDS bounce)
// Swapped GEMM2: lane holds batch-row=l&15, out-col=16*cf+4*(l>>4)+i -> joint lane-local.
//
// R20 = R12/R19 fused_main (measured optimum: 124-126 us) + prep/fixup overhead trim.
// Design-space conclusion (R7-R18): combined VGPR+AGPR live set caps occupancy at
// 16 waves/CU; all pipes <=45%; schedule variants 124-166 us. Family optimum.

__global__ __launch_bounds__(256)
void prep(const float* __restrict__ W1, const float* __restrict__ W2,
          _Float16* __restrict__ ws, int* __restrict__ flags) {
    int t0 = blockIdx.x * 256 + threadIdx.x;    // 0..11263, each does 2 fragment slots
    if (t0 == 0) flags[0] = 0;
    #pragma unroll
    for (int half = 0; half < 2; ++half) {
        int t = t0 + half * 11264;              // 0..22527
        if (t < 16384) {
            int lane = t & 63;
            int cfrag = (t >> 6) & 1;
            int ks = (t >> 7) & 7;
            int ckI = t >> 10;
            int c = ckI * 32 + cfrag * 16 + (lane & 15);
            int kb = ks * 32 + 4 * (lane >> 4);
            half8 v;
            #pragma unroll
            for (int j = 0; j < 8; ++j) {
                int k = kb + (j & 3) + 16 * (j >> 2);
                v[j] = (_Float16)W1[k * HH + c];
            }
            *(half8*)(ws + t * 8) = v;
        } else if (t < 16384 + 6144) {
            int u = t - 16384;
            int lane = u & 63;
            int rest = u >> 6;                  // 0..95
            int cfrag = rest % 6;
            int ckI = rest / 6;
            int c = cfrag * 16 + (lane & 15);   // 0..95
            int kb = ckI * 32 + 4 * (lane >> 4);
            half8 v;
            #pragma unroll
            for (int j = 0; j < 8; ++j) {
                int k = kb + (j & 3) + 16 * (j >> 2);
                v[j] = (c < OC) ? (_Float16)W2[k * OC + c] : (_Float16)0.0f;
            }
            *(half8*)(ws + W2_OFF + (ckI * 6 + cfrag) * 512 + lane * 8) = v;
        }
    }
}

__global__ __launch_bounds__(256)
__attribute__((amdgpu_waves_per_eu(4)))
void fused_main(const float* __restrict__ z, const _Float16* __restrict__ wsp,
                const float* __restrict__ b1, const float* __restrict__ b2,
                float* __restrict__ out, long long Btot, int* __restrict__ flags)
{
    // LDS: [0,32768) W1 double-buffer (epilogue aliases [0,24320): 4 x 6080 B per wave)
    //      [32768,34816) b1f | [34816,35200) b2f
    __shared__ __align__(16) char smem[35200];   // -> 4 blocks/CU by LDS
    float* b1f = (float*)(smem + 32768);
    float* b2f = (float*)(smem + 34816);
    const int tid = threadIdx.x;
    const int w   = tid >> 6;          // 0..3
    const int l   = tid & 63;
    const int l15 = l & 15;
    const int l4  = l >> 4;

    const long long R0w = (long long)blockIdx.x * BM + w * 16;

// async stage of one chunk's W1 frags (16 x 1KB granules; wave w does 4)
#define STAGE(ck_, dstbuf_) do {                                                             \
    const char* s1g_ = (const char*)wsp + (size_t)(ck_) * 16384;                             \
    _Pragma("unroll")                                                                        \
    for (int i_ = 0; i_ < 4; ++i_) {                                                         \
        int g_ = w * 4 + i_;                                                                 \
        __builtin_amdgcn_global_load_lds(                                                    \
            (const __attribute__((address_space(1))) void*)(s1g_ + g_ * 1024 + l * 16),      \
            (__attribute__((address_space(3))) void*)((dstbuf_) + g_ * 1024), 16, 0, 0);     \
    }                                                                                        \
} while (0)

#define MF(a_, b_, c_) __builtin_amdgcn_mfma_f32_16x16x32_f16((a_), (b_), (c_), 0, 0, 0)

// 16 rows/wave. w2f global loads hoisted BEFORE GEMM1 (L2 latency hides under MFMAs).
#define COMPUTE_CHUNK(bufc_, ck_) do {                                                       \
    const _Float16* s1_ = (const _Float16*)(bufc_);                                          \
    const _Float16* p2_ = wsp + W2_OFF + (ck_) * 3072 + l * 8;                               \
    half8 w2f_[6];                                                                           \
    _Pragma("unroll")                                                                        \
    for (int cf_ = 0; cf_ < 6; ++cf_) w2f_[cf_] = *(const half8*)(p2_ + cf_ * 512);          \
    floatx4 acc1_[2];                                                                        \
    acc1_[0] = (floatx4)0.0f; acc1_[1] = (floatx4)0.0f;                                      \
    _Pragma("unroll")                                                                        \
    for (int ks_ = 0; ks_ < 8; ++ks_) {                                                      \
        _Pragma("unroll")                                                                    \
        for (int cf_ = 0; cf_ < 2; ++cf_) {                                                  \
            half8 bh_ = *(const half8*)(s1_ + ((ks_ * 2 + cf_) * 64 + l) * 8);               \
            acc1_[cf_] = MF(bh_, zh[ks_], acc1_[cf_]);                                       \
        }                                                                                    \
    }                                                                                        \
    floatx4 vb1a_ = *(const floatx4*)(b1f + (ck_) * 32 + 4 * l4);                            \
    floatx4 vb1b_ = *(const floatx4*)(b1f + (ck_) * 32 + 16 + 4 * l4);                       \
    half8 ah_;                                                                               \
    _Pragma("unroll")                                                                        \
    for (int cf_ = 0; cf_ < 2; ++cf_) {                                                      \
        _Pragma("unroll")                                                                    \
        for (int i_ = 0; i_ < 4; ++i_) {                                                     \
            float a_ = acc1_[cf_][i_] + (cf_ ? vb1b_[i_] : vb1a_[i_]);                       \
            float hv_ = a_ * __builtin_amdgcn_rcpf(1.0f + __expf(-a_));                      \
            ah_[i_ | (cf_ << 2)] = (_Float16)hv_;                                            \
        }                                                                                    \
    }                                                                                        \
    _Pragma("unroll")                                                                        \
    for (int cf_ = 0; cf_ < 6; ++cf_) {                                                      \
        a2[cf_] = MF(w2f_[cf_], ah_, a2[cf_]);                                               \
    }                                                                                        \
} while (0)

    // ---- prologue: stage chunk 0, biases to LDS, z fragments to regs ----
    STAGE(0, smem);
    if (tid < 128) *(floatx4*)(b1f + tid * 4) = *(const floatx4*)(b1 + tid * 4);
    if (tid >= 128 && tid < 224) { int c = tid - 128; b2f[c] = (c < OC) ? b2[c] : 0.0f; }

    half8 zh[8];
    {
        const float* zrow = z + (R0w + l15) * DD;
        #pragma unroll
        for (int ks = 0; ks < 8; ++ks) {
            const float* p = zrow + ks * 32 + l4 * 4;
            floatx4 va = *(const floatx4*)p;
            floatx4 vb = *(const floatx4*)(p + 16);
            half8 th;
            th[0] = (_Float16)va[0]; th[1] = (_Float16)va[1];
            th[2] = (_Float16)va[2]; th[3] = (_Float16)va[3];
            th[4] = (_Float16)vb[0]; th[5] = (_Float16)vb[1];
            th[6] = (_Float16)vb[2]; th[7] = (_Float16)vb[3];
            zh[ks] = th;
        }
    }

    floatx4 a2[6];
    #pragma unroll
    for (int i = 0; i < 6; ++i) a2[i] = (floatx4)0.0f;

    __syncthreads();   // drains stage-0 DMA + bias writes

    // ---- main loop: double-buffered, one vmcnt(0)+barrier per chunk ----
    #pragma unroll 1
    for (int t = 0; t < 8; ++t) {
        STAGE(2 * t + 1, smem + BUF_BYTES);
        COMPUTE_CHUNK(smem, 2 * t);
        asm volatile("s_waitcnt vmcnt(0)" ::: "memory");
        __builtin_amdgcn_s_barrier();
        if (t < 7) STAGE(2 * t + 2, smem);
        COMPUTE_CHUNK(smem + BUF_BYTES, 2 * t + 1);
        asm volatile("s_waitcnt vmcnt(0)" ::: "memory");
        __builtin_amdgcn_s_barrier();
    }

    float* joints  = out;
    float* offsets = out + Btot * (NJ * 3);
    float* length  = out + 2 * Btot * (NJ * 3);

    // ---- epilogue: wave-private 6080-B LDS region (aliases dbuf) ----
    {
        float* s_off = (float*)(smem + w * 6080);       // [16][72] f32
        float* s_len = s_off + 1152;                    // [16][23] f32
        const int r = l15;
        #pragma unroll
        for (int cf = 0; cf < 6; ++cf) {
            const int j = 4 * cf + l4;                  // joint-1 index
            if (j < NJ - 1) {
                float x  = a2[cf][0] + b2f[4 * j + 0];
                float y  = a2[cf][1] + b2f[4 * j + 1];
                float zz = a2[cf][2] + b2f[4 * j + 2];
                float lr = a2[cf][3] + b2f[4 * j + 3];
                float nrm = sqrtf(x * x + y * y + zz * zz);
                float inv = __builtin_amdgcn_rcpf(fmaxf(nrm, 1e-6f));
                float len = fmaxf(lr, 0.0f) + __logf(1.0f + __expf(-fabsf(lr)));
                if (len > 12.0f * nrm) {                // fp16 path untrustworthy here
                    int fi = atomicAdd(&flags[0], 1);
                    if (fi < FCAP) flags[1 + fi] = (int)(R0w + r);
                }
                s_off[r * 72 + 3 * (j + 1) + 0] = x * inv * len;
                s_off[r * 72 + 3 * (j + 1) + 1] = y * inv * len;
                s_off[r * 72 + 3 * (j + 1) + 2] = zz * inv * len;
                s_len[r * 23 + j] = len;
            }
        }
        if (l < 16) {
            s_off[l * 72 + 0] = 0.0f;
            s_off[l * 72 + 1] = 0.0f;
            s_off[l * 72 + 2] = 0.0f;
        }
        __syncthreads();    // (also orders the per-wave LDS write->read)

        // offsets: coalesced float4 copy (16 rows x 72 = 288 float4)
        {
            float* gdst = offsets + R0w * (NJ * 3);
            for (int t4 = l; t4 < 288; t4 += 64)
                *(float4*)(gdst + t4 * 4) = *(float4*)(s_off + t4 * 4);
        }
        // lengths: 16 x 23 = 368 f32 = 92 float4
        {
            float* gdst = length + R0w * (NJ - 1);
            for (int t4 = l; t4 < 92; t4 += 64)
                *(float4*)(gdst + t4 * 4) = *(float4*)(s_len + t4 * 4);
        }
        // joints: per-lane ancestor chain walk (16 x 24 = 384 tasks)
        for (int task = l; task < 16 * NJ; task += 64) {
            int rr = task / NJ;
            int j = task - rr * NJ;
            float jx = 0.0f, jy = 0.0f, jz = 0.0f;
            int k = j;
            while (k > 0) {
                jx += s_off[rr * 72 + 3 * k + 0];
                jy += s_off[rr * 72 + 3 * k + 1];
                jz += s_off[rr * 72 + 3 * k + 2];
                k = c_parent[k];
            }
            long long base = (R0w + rr) * (NJ * 3) + j * 3;
            joints[base + 0] = jx;
            joints[base + 1] = jy;
            joints[base + 2] = jz;
        }
    }
#undef STAGE
#undef COMPUTE_CHUNK
#undef MF
}

// exact fp32 recompute of flagged rows; grid-stride over flagged list
__global__ __launch_bounds__(256)
void fixup(const float* __restrict__ z, const float* __restrict__ W1,
           const float* __restrict__ b1, const float* __restrict__ W2,
           const float* __restrict__ b2, float* __restrict__ out,
           long long Btot, const int* __restrict__ flags)
{
    __shared__ float z_s[DD];
    __shared__ float h_s[HH];
    __shared__ float raw_s[96];
    __shared__ float off_s[72];
    int n = flags[0];
    if (n > FCAP) n = FCAP;
    const int tid = threadIdx.x;

    float* joints  = out;
    float* offsets = out + Btot * (NJ * 3);
    float* length  = out + 2 * Btot * (NJ * 3);

    for (int e = blockIdx.x; e < n; e += gridDim.x) {
        const long long row = flags[1 + e];
        __syncthreads();
        z_s[tid] = z[row * DD + tid];
        __syncthreads();
        for (int c = tid; c < HH; c += 256) {
            float acc = b1[c];
            for (int k = 0; k < DD; ++k) acc = fmaf(z_s[k], W1[k * HH + c], acc);
            h_s[c] = acc / (1.0f + expf(-acc));
        }
        __syncthreads();
        if (tid < OC) {
            float acc = b2[tid];
            for (int k = 0; k < HH; ++k) acc = fmaf(h_s[k], W2[k * OC + tid], acc);
            raw_s[tid] = acc;
        }
        __syncthreads();
        if (tid < NJ - 1) {
            int j = tid;
            float x  = raw_s[4 * j + 0];
            float y  = raw_s[4 * j + 1];
            float zz = raw_s[4 * j + 2];
            float lr = raw_s[4 * j + 3];
            float nrm = sqrtf(x * x + y * y + zz * zz);
            float inv = 1.0f / fmaxf(nrm, 1e-6f);
            float len = fmaxf(lr, 0.0f) + log1pf(expf(-fabsf(lr)));
            off_s[3 * (j + 1) + 0] = x * inv * len;
            off_s[3 * (j + 1) + 1] = y * inv * len;
            off_s[3 * (j + 1) + 2] = zz * inv * len;
            length[row * (NJ - 1) + j] = len;
        }
        if (tid < 3) off_s[tid] = 0.0f;
        __syncthreads();
        if (tid < NJ) {
            int j = tid;
            float jx = 0.0f, jy = 0.0f, jz = 0.0f;
            int k = j;
            while (k > 0) {
                jx += off_s[3 * k + 0];
                jy += off_s[3 * k + 1];
                jz += off_s[3 * k + 2];
                k = c_parent[k];
            }
            joints[row * (NJ * 3) + j * 3 + 0] = jx;
            joints[row * (NJ * 3) + j * 3 + 1] = jy;
            joints[row * (NJ * 3) + j * 3 + 2] = jz;
        }
        if (tid < NJ * 3) offsets[row * (NJ * 3) + tid] = off_s[tid];
    }
}

extern "C" void kernel_launch(void* const* d_in, const int* in_sizes, int n_in,
                              void* d_out, int out_size, void* d_ws, size_t ws_size,
                              hipStream_t stream) {
    const float* z  = (const float*)d_in[0];
    const float* W1 = (const float*)d_in[1];
    const float* b1 = (const float*)d_in[2];
    const float* W2 = (const float*)d_in[3];
    const float* b2 = (const float*)d_in[4];
    float* out = (float*)d_out;
    _Float16* ws = (_Float16*)d_ws;
    int* flags = (int*)(ws + FLAG_OFF);

    const long long Btot = (long long)in_sizes[0] / DD;   // 131072

    prep<<<44, 256, 0, stream>>>(W1, W2, ws, flags);
    fused_main<<<(int)(Btot / BM), 256, 0, stream>>>(z, ws, b1, b2, out, Btot, flags);
    fixup<<<256, 256, 0, stream>>>(z, W1, b1, W2, b2, out, Btot, flags);
}

// Round 21
// 143.296 us; speedup vs baseline: 1.4492x; 1.4492x over previous
//
#include <hip/hip_runtime.h>
#include <math.h>

typedef _Float16 half8 __attribute__((ext_vector_type(8)));
typedef float floatx4 __attribute__((ext_vector_type(4)));

#define DD 256
#define HH 512
#define OC 92
#define NJ 24
#define BM 64                  // rows per block (4 waves x 16)
#define NCHUNK 16
#define W2_OFF 131072          // halfs: compact W2 frag region (16 chunks x 3072 halfs)
#define FLAG_OFF 180224        // halfs offset of int flag block
#define FCAP 16384
#define BUF_BYTES 16384        // W1 chunk (W2 read global->reg)

__constant__ int c_parent[NJ] = {-1,0,0,0,1,2,3,4,5,6,7,8,9,9,9,12,13,14,16,17,18,19,20,21};

// fragment maps (verified R2-R19):
// A/B-frag: lane l holds (non-K idx)=l&15, k = 4*(l>>4)+(j&3)+16*(j>>2)
// C/D: reg i: M-idx = 4*(l>>4)+i, N-idx = l&15
// Swapped GEMM1: mfma(W1frag, zfrag) -> lane holds batch-row=l&15, h-col=16*cf+4*(l>>4)+i
//   == GEMM2 B-frag with j = i|(cf<<2)  (register handoff, no LDS bounce)
// Swapped GEMM2: lane holds batch-row=l&15, out-col=16*cf+4*(l>>4)+i -> joint lane-local.
//
// R21 = exact revert to R19/R12 (measured best: 124-126 us main / 143.6-144.0 harness).
// R20's prep/fixup grid shrink regressed harness 144->208 (latency-bound small kernels
// need parallelism). Design-space conclusion (R7-R20): this config is the optimum.

__global__ __launch_bounds__(256)
void prep(const float* __restrict__ W1, const float* __restrict__ W2,
          _Float16* __restrict__ ws, int* __restrict__ flags) {
    int t = blockIdx.x * 256 + threadIdx.x;     // 0..22527
    if (t == 0) flags[0] = 0;
    if (t < 16384) {
        int lane = t & 63;
        int cfrag = (t >> 6) & 1;
        int ks = (t >> 7) & 7;
        int ckI = t >> 10;
        int c = ckI * 32 + cfrag * 16 + (lane & 15);
        int kb = ks * 32 + 4 * (lane >> 4);
        half8 v;
        #pragma unroll
        for (int j = 0; j < 8; ++j) {
            int k = kb + (j & 3) + 16 * (j >> 2);
            v[j] = (_Float16)W1[k * HH + c];
        }
        *(half8*)(ws + t * 8) = v;
    } else if (t < 16384 + 6144) {
        int u = t - 16384;
        int lane = u & 63;
        int rest = u >> 6;                      // 0..95
        int cfrag = rest % 6;
        int ckI = rest / 6;
        int c = cfrag * 16 + (lane & 15);       // 0..95
        int kb = ckI * 32 + 4 * (lane >> 4);
        half8 v;
        #pragma unroll
        for (int j = 0; j < 8; ++j) {
            int k = kb + (j & 3) + 16 * (j >> 2);
            v[j] = (c < OC) ? (_Float16)W2[k * OC + c] : (_Float16)0.0f;
        }
        *(half8*)(ws + W2_OFF + (ckI * 6 + cfrag) * 512 + lane * 8) = v;
    }
}

__global__ __launch_bounds__(256)
__attribute__((amdgpu_waves_per_eu(4)))
void fused_main(const float* __restrict__ z, const _Float16* __restrict__ wsp,
                const float* __restrict__ b1, const float* __restrict__ b2,
                float* __restrict__ out, long long Btot, int* __restrict__ flags)
{
    // LDS: [0,32768) W1 double-buffer (epilogue aliases [0,24320): 4 x 6080 B per wave)
    //      [32768,34816) b1f | [34816,35200) b2f
    __shared__ __align__(16) char smem[35200];   // -> 4 blocks/CU by LDS
    float* b1f = (float*)(smem + 32768);
    float* b2f = (float*)(smem + 34816);
    const int tid = threadIdx.x;
    const int w   = tid >> 6;          // 0..3
    const int l   = tid & 63;
    const int l15 = l & 15;
    const int l4  = l >> 4;

    const long long R0w = (long long)blockIdx.x * BM + w * 16;

// async stage of one chunk's W1 frags (16 x 1KB granules; wave w does 4)
#define STAGE(ck_, dstbuf_) do {                                                             \
    const char* s1g_ = (const char*)wsp + (size_t)(ck_) * 16384;                             \
    _Pragma("unroll")                                                                        \
    for (int i_ = 0; i_ < 4; ++i_) {                                                         \
        int g_ = w * 4 + i_;                                                                 \
        __builtin_amdgcn_global_load_lds(                                                    \
            (const __attribute__((address_space(1))) void*)(s1g_ + g_ * 1024 + l * 16),      \
            (__attribute__((address_space(3))) void*)((dstbuf_) + g_ * 1024), 16, 0, 0);     \
    }                                                                                        \
} while (0)

#define MF(a_, b_, c_) __builtin_amdgcn_mfma_f32_16x16x32_f16((a_), (b_), (c_), 0, 0, 0)

// 16 rows/wave. w2f global loads hoisted BEFORE GEMM1 (L2 latency hides under MFMAs).
#define COMPUTE_CHUNK(bufc_, ck_) do {                                                       \
    const _Float16* s1_ = (const _Float16*)(bufc_);                                          \
    const _Float16* p2_ = wsp + W2_OFF + (ck_) * 3072 + l * 8;                               \
    half8 w2f_[6];                                                                           \
    _Pragma("unroll")                                                                        \
    for (int cf_ = 0; cf_ < 6; ++cf_) w2f_[cf_] = *(const half8*)(p2_ + cf_ * 512);          \
    floatx4 acc1_[2];                                                                        \
    acc1_[0] = (floatx4)0.0f; acc1_[1] = (floatx4)0.0f;                                      \
    _Pragma("unroll")                                                                        \
    for (int ks_ = 0; ks_ < 8; ++ks_) {                                                      \
        _Pragma("unroll")                                                                    \
        for (int cf_ = 0; cf_ < 2; ++cf_) {                                                  \
            half8 bh_ = *(const half8*)(s1_ + ((ks_ * 2 + cf_) * 64 + l) * 8);               \
            acc1_[cf_] = MF(bh_, zh[ks_], acc1_[cf_]);                                       \
        }                                                                                    \
    }                                                                                        \
    floatx4 vb1a_ = *(const floatx4*)(b1f + (ck_) * 32 + 4 * l4);                            \
    floatx4 vb1b_ = *(const floatx4*)(b1f + (ck_) * 32 + 16 + 4 * l4);                       \
    half8 ah_;                                                                               \
    _Pragma("unroll")                                                                        \
    for (int cf_ = 0; cf_ < 2; ++cf_) {                                                      \
        _Pragma("unroll")                                                                    \
        for (int i_ = 0; i_ < 4; ++i_) {                                                     \
            float a_ = acc1_[cf_][i_] + (cf_ ? vb1b_[i_] : vb1a_[i_]);                       \
            float hv_ = a_ * __builtin_amdgcn_rcpf(1.0f + __expf(-a_));                      \
            ah_[i_ | (cf_ << 2)] = (_Float16)hv_;                                            \
        }                                                                                    \
    }                                                                                        \
    _Pragma("unroll")                                                                        \
    for (int cf_ = 0; cf_ < 6; ++cf_) {                                                      \
        a2[cf_] = MF(w2f_[cf_], ah_, a2[cf_]);                                               \
    }                                                                                        \
} while (0)

    // ---- prologue: stage chunk 0, biases to LDS, z fragments to regs ----
    STAGE(0, smem);
    if (tid < 128) *(floatx4*)(b1f + tid * 4) = *(const floatx4*)(b1 + tid * 4);
    if (tid >= 128 && tid < 224) { int c = tid - 128; b2f[c] = (c < OC) ? b2[c] : 0.0f; }

    half8 zh[8];
    {
        const float* zrow = z + (R0w + l15) * DD;
        #pragma unroll
        for (int ks = 0; ks < 8; ++ks) {
            const float* p = zrow + ks * 32 + l4 * 4;
            floatx4 va = *(const floatx4*)p;
            floatx4 vb = *(const floatx4*)(p + 16);
            half8 th;
            th[0] = (_Float16)va[0]; th[1] = (_Float16)va[1];
            th[2] = (_Float16)va[2]; th[3] = (_Float16)va[3];
            th[4] = (_Float16)vb[0]; th[5] = (_Float16)vb[1];
            th[6] = (_Float16)vb[2]; th[7] = (_Float16)vb[3];
            zh[ks] = th;
        }
    }

    floatx4 a2[6];
    #pragma unroll
    for (int i = 0; i < 6; ++i) a2[i] = (floatx4)0.0f;

    __syncthreads();   // drains stage-0 DMA + bias writes

    // ---- main loop: double-buffered, one vmcnt(0)+barrier per chunk ----
    #pragma unroll 1
    for (int t = 0; t < 8; ++t) {
        STAGE(2 * t + 1, smem + BUF_BYTES);
        COMPUTE_CHUNK(smem, 2 * t);
        asm volatile("s_waitcnt vmcnt(0)" ::: "memory");
        __builtin_amdgcn_s_barrier();
        if (t < 7) STAGE(2 * t + 2, smem);
        COMPUTE_CHUNK(smem + BUF_BYTES, 2 * t + 1);
        asm volatile("s_waitcnt vmcnt(0)" ::: "memory");
        __builtin_amdgcn_s_barrier();
    }

    float* joints  = out;
    float* offsets = out + Btot * (NJ * 3);
    float* length  = out + 2 * Btot * (NJ * 3);

    // ---- epilogue: wave-private 6080-B LDS region (aliases dbuf) ----
    {
        float* s_off = (float*)(smem + w * 6080);       // [16][72] f32
        float* s_len = s_off + 1152;                    // [16][23] f32
        const int r = l15;
        #pragma unroll
        for (int cf = 0; cf < 6; ++cf) {
            const int j = 4 * cf + l4;                  // joint-1 index
            if (j < NJ - 1) {
                float x  = a2[cf][0] + b2f[4 * j + 0];
                float y  = a2[cf][1] + b2f[4 * j + 1];
                float zz = a2[cf][2] + b2f[4 * j + 2];
                float lr = a2[cf][3] + b2f[4 * j + 3];
                float nrm = sqrtf(x * x + y * y + zz * zz);
                float inv = __builtin_amdgcn_rcpf(fmaxf(nrm, 1e-6f));
                float len = fmaxf(lr, 0.0f) + __logf(1.0f + __expf(-fabsf(lr)));
                if (len > 12.0f * nrm) {                // fp16 path untrustworthy here
                    int fi = atomicAdd(&flags[0], 1);
                    if (fi < FCAP) flags[1 + fi] = (int)(R0w + r);
                }
                s_off[r * 72 + 3 * (j + 1) + 0] = x * inv * len;
                s_off[r * 72 + 3 * (j + 1) + 1] = y * inv * len;
                s_off[r * 72 + 3 * (j + 1) + 2] = zz * inv * len;
                s_len[r * 23 + j] = len;
            }
        }
        if (l < 16) {
            s_off[l * 72 + 0] = 0.0f;
            s_off[l * 72 + 1] = 0.0f;
            s_off[l * 72 + 2] = 0.0f;
        }
        __syncthreads();    // (also orders the per-wave LDS write->read)

        // offsets: coalesced float4 copy (16 rows x 72 = 288 float4)
        {
            float* gdst = offsets + R0w * (NJ * 3);
            for (int t4 = l; t4 < 288; t4 += 64)
                *(float4*)(gdst + t4 * 4) = *(float4*)(s_off + t4 * 4);
        }
        // lengths: 16 x 23 = 368 f32 = 92 float4
        {
            float* gdst = length + R0w * (NJ - 1);
            for (int t4 = l; t4 < 92; t4 += 64)
                *(float4*)(gdst + t4 * 4) = *(float4*)(s_len + t4 * 4);
        }
        // joints: per-lane ancestor chain walk (16 x 24 = 384 tasks)
        for (int task = l; task < 16 * NJ; task += 64) {
            int rr = task / NJ;
            int j = task - rr * NJ;
            float jx = 0.0f, jy = 0.0f, jz = 0.0f;
            int k = j;
            while (k > 0) {
                jx += s_off[rr * 72 + 3 * k + 0];
                jy += s_off[rr * 72 + 3 * k + 1];
                jz += s_off[rr * 72 + 3 * k + 2];
                k = c_parent[k];
            }
            long long base = (R0w + rr) * (NJ * 3) + j * 3;
            joints[base + 0] = jx;
            joints[base + 1] = jy;
            joints[base + 2] = jz;
        }
    }
#undef STAGE
#undef COMPUTE_CHUNK
#undef MF
}

// exact fp32 recompute of flagged rows; one block per flagged row
__global__ __launch_bounds__(256)
void fixup(const float* __restrict__ z, const float* __restrict__ W1,
           const float* __restrict__ b1, const float* __restrict__ W2,
           const float* __restrict__ b2, float* __restrict__ out,
           long long Btot, const int* __restrict__ flags)
{
    __shared__ float z_s[DD];
    __shared__ float h_s[HH];
    __shared__ float raw_s[96];
    __shared__ float off_s[72];
    int n = flags[0];
    if (n > FCAP) n = FCAP;
    if ((int)blockIdx.x >= n) return;
    const int tid = threadIdx.x;
    const long long row = flags[1 + blockIdx.x];

    float* joints  = out;
    float* offsets = out + Btot * (NJ * 3);
    float* length  = out + 2 * Btot * (NJ * 3);

    z_s[tid] = z[row * DD + tid];
    __syncthreads();
    for (int c = tid; c < HH; c += 256) {
        float acc = b1[c];
        for (int k = 0; k < DD; ++k) acc = fmaf(z_s[k], W1[k * HH + c], acc);
        h_s[c] = acc / (1.0f + expf(-acc));
    }
    __syncthreads();
    if (tid < OC) {
        float acc = b2[tid];
        for (int k = 0; k < HH; ++k) acc = fmaf(h_s[k], W2[k * OC + tid], acc);
        raw_s[tid] = acc;
    }
    __syncthreads();
    if (tid < NJ - 1) {
        int j = tid;
        float x  = raw_s[4 * j + 0];
        float y  = raw_s[4 * j + 1];
        float zz = raw_s[4 * j + 2];
        float lr = raw_s[4 * j + 3];
        float nrm = sqrtf(x * x + y * y + zz * zz);
        float inv = 1.0f / fmaxf(nrm, 1e-6f);
        float len = fmaxf(lr, 0.0f) + log1pf(expf(-fabsf(lr)));
        off_s[3 * (j + 1) + 0] = x * inv * len;
        off_s[3 * (j + 1) + 1] = y * inv * len;
        off_s[3 * (j + 1) + 2] = zz * inv * len;
        length[row * (NJ - 1) + j] = len;
    }
    if (tid < 3) off_s[tid] = 0.0f;
    __syncthreads();
    if (tid < NJ) {
        int j = tid;
        float jx = 0.0f, jy = 0.0f, jz = 0.0f;
        int k = j;
        while (k > 0) {
            jx += off_s[3 * k + 0];
            jy += off_s[3 * k + 1];
            jz += off_s[3 * k + 2];
            k = c_parent[k];
        }
        joints[row * (NJ * 3) + j * 3 + 0] = jx;
        joints[row * (NJ * 3) + j * 3 + 1] = jy;
        joints[row * (NJ * 3) + j * 3 + 2] = jz;
    }
    if (tid < NJ * 3) offsets[row * (NJ * 3) + tid] = off_s[tid];
}

extern "C" void kernel_launch(void* const* d_in, const int* in_sizes, int n_in,
                              void* d_out, int out_size, void* d_ws, size_t ws_size,
                              hipStream_t stream) {
    const float* z  = (const float*)d_in[0];
    const float* W1 = (const float*)d_in[1];
    const float* b1 = (const float*)d_in[2];
    const float* W2 = (const float*)d_in[3];
    const float* b2 = (const float*)d_in[4];
    float* out = (float*)d_out;
    _Float16* ws = (_Float16*)d_ws;
    int* flags = (int*)(ws + FLAG_OFF);

    const long long Btot = (long long)in_sizes[0] / DD;   // 131072

    prep<<<88, 256, 0, stream>>>(W1, W2, ws, flags);
    fused_main<<<(int)(Btot / BM), 256, 0, stream>>>(z, ws, b1, b2, out, Btot, flags);
    fixup<<<4096, 256, 0, stream>>>(z, W1, b1, W2, b2, out, Btot, flags);
}